// Round 4
// baseline (451.996 us; speedup 1.0000x reference)
//
#include <hip/hip_runtime.h>
#include <math.h>

#define BATCH 16
#define KCLS  19
#define CCH   512
#define HW    16384

#define SC    512          // hw staged per step
#define NSTEP (HW / SC)    // 32 steps, full HW per block
#define RPW   5            // ceil(KCLS/4) probs rows handled per wave

// ---------------- Kernel A: per-(b,k) softmax stats (max, 1/sum) ----------------
__global__ __launch_bounds__(256) void softmax_stats_kernel(
    const float* __restrict__ probs, float* __restrict__ stats) {
  const int bk = blockIdx.x;                      // 0..303
  const float4* row = (const float4*)(probs + (size_t)bk * HW);
  const int tid  = threadIdx.x;
  const int lane = tid & 63;
  const int wave = tid >> 6;
  __shared__ float red[4];

  float m = -1e30f;
  for (int i = tid; i < HW / 4; i += 256) {
    float4 v = row[i];
    m = fmaxf(m, fmaxf(fmaxf(v.x, v.y), fmaxf(v.z, v.w)));
  }
  for (int off = 32; off > 0; off >>= 1) m = fmaxf(m, __shfl_xor(m, off));
  if (lane == 0) red[wave] = m;
  __syncthreads();
  m = fmaxf(fmaxf(red[0], red[1]), fmaxf(red[2], red[3]));

  float s = 0.f;
  for (int i = tid; i < HW / 4; i += 256) {
    float4 v = row[i];
    s += __expf(v.x - m) + __expf(v.y - m) + __expf(v.z - m) + __expf(v.w - m);
  }
  for (int off = 32; off > 0; off >>= 1) s += __shfl_xor(s, off);
  __syncthreads();
  if (lane == 0) red[wave] = s;
  __syncthreads();
  if (tid == 0) {
    float total = red[0] + red[1] + red[2] + red[3];
    stats[2 * bk]     = m;
    stats[2 * bk + 1] = 1.0f / total;
  }
}

// ---------------- Kernel B: ctx[b,k,c] = sum_hw attn * feat ----------------
// 512 blocks x 256 thr = 2048 waves = exact full residency at 2 waves/SIMD.
// bid&15 = b -> bid%8 = b%8: each batch's 32 blocks share one XCD (probs L2-hot).
// Pipeline per step s: [issue probs loads for s+1] [GEMM on buf[s&1]]
// [exp -> ds_write buf[s&1^1]] [one barrier]. Probs latency hides under GEMM.
__global__ __launch_bounds__(256, 2) void gather_kernel(
    const float* __restrict__ feat, const float* __restrict__ probs,
    const float* __restrict__ stats, float* __restrict__ out) {
  __shared__ float attn[2][KCLS][SC];   // 76 KB -> 2 blocks/CU = 152 KB

  const int bid   = blockIdx.x;
  const int b     = bid & 15;
  const int ctile = bid >> 4;          // 0..31
  const int tid   = threadIdx.x;
  const int wave  = tid >> 6;          // 4 waves
  const int lane  = tid & 63;
  const int c0    = ctile * 16 + wave * 4;

  // this wave's probs rows: k = wave + 4r (r<5); clamp dead row 19 -> 18
  int   kk[RPW];  bool act[RPW];  float smr[RPW], sir[RPW];
  #pragma unroll
  for (int r = 0; r < RPW; r++) {
    int k   = wave + 4 * r;
    act[r]  = (k < KCLS);
    kk[r]   = act[r] ? k : (KCLS - 1);
    smr[r]  = stats[2 * (b * KCLS + kk[r])];
    sir[r]  = stats[2 * (b * KCLS + kk[r]) + 1];
  }

  const float* fp = feat + ((size_t)(b * CCH + c0)) * HW;
  const float* pb = probs + (size_t)b * KCLS * HW;

  float acc[KCLS][4];
  #pragma unroll
  for (int k = 0; k < KCLS; k++)
    #pragma unroll
    for (int j = 0; j < 4; j++) acc[k][j] = 0.f;

  float4 pr0[RPW], pr1[RPW];

  // ---- prologue: stage step 0 into buf 0 ----
  #pragma unroll
  for (int r = 0; r < RPW; r++) {
    const float* pk = pb + (size_t)kk[r] * HW;
    pr0[r] = *(const float4*)(pk + lane * 4);
    pr1[r] = *(const float4*)(pk + 256 + lane * 4);
  }
  #pragma unroll
  for (int r = 0; r < RPW; r++) {
    if (act[r]) {
      float m = smr[r], iv = sir[r];
      float4 a0, a1;
      a0.x = __expf(pr0[r].x - m) * iv;  a0.y = __expf(pr0[r].y - m) * iv;
      a0.z = __expf(pr0[r].z - m) * iv;  a0.w = __expf(pr0[r].w - m) * iv;
      a1.x = __expf(pr1[r].x - m) * iv;  a1.y = __expf(pr1[r].y - m) * iv;
      a1.z = __expf(pr1[r].z - m) * iv;  a1.w = __expf(pr1[r].w - m) * iv;
      *(float4*)&attn[0][kk[r]][lane * 4]       = a0;
      *(float4*)&attn[0][kk[r]][256 + lane * 4] = a1;
    }
  }
  __syncthreads();

  // ---- main pipeline ----
  for (int s = 0; s < NSTEP; s++) {
    const int cur = s & 1, nxt = cur ^ 1;
    const int sn  = (s + 1 < NSTEP ? s + 1 : s) * SC;   // clamped prefetch target

    // (1) issue probs loads for step s+1 (latency hidden under GEMM)
    #pragma unroll
    for (int r = 0; r < RPW; r++) {
      const float* pk = pb + (size_t)kk[r] * HW + sn;
      pr0[r] = *(const float4*)(pk + lane * 4);
      pr1[r] = *(const float4*)(pk + 256 + lane * 4);
    }

    // (2) GEMM on buf[cur]
    const float* fs = fp + s * SC;
    const float (*bufc)[SC] = attn[cur];
    #pragma unroll
    for (int it = 0; it < SC; it += 256) {
      const int hw = it + lane * 4;
      float4 f0 = *(const float4*)(fs + (size_t)0 * HW + hw);
      float4 f1 = *(const float4*)(fs + (size_t)1 * HW + hw);
      float4 f2 = *(const float4*)(fs + (size_t)2 * HW + hw);
      float4 f3 = *(const float4*)(fs + (size_t)3 * HW + hw);
      #pragma unroll
      for (int k = 0; k < KCLS; k++) {
        float4 a = *(const float4*)&bufc[k][hw];
        acc[k][0] = fmaf(a.x, f0.x, acc[k][0]);
        acc[k][0] = fmaf(a.y, f0.y, acc[k][0]);
        acc[k][0] = fmaf(a.z, f0.z, acc[k][0]);
        acc[k][0] = fmaf(a.w, f0.w, acc[k][0]);
        acc[k][1] = fmaf(a.x, f1.x, acc[k][1]);
        acc[k][1] = fmaf(a.y, f1.y, acc[k][1]);
        acc[k][1] = fmaf(a.z, f1.z, acc[k][1]);
        acc[k][1] = fmaf(a.w, f1.w, acc[k][1]);
        acc[k][2] = fmaf(a.x, f2.x, acc[k][2]);
        acc[k][2] = fmaf(a.y, f2.y, acc[k][2]);
        acc[k][2] = fmaf(a.z, f2.z, acc[k][2]);
        acc[k][2] = fmaf(a.w, f2.w, acc[k][2]);
        acc[k][3] = fmaf(a.x, f3.x, acc[k][3]);
        acc[k][3] = fmaf(a.y, f3.y, acc[k][3]);
        acc[k][3] = fmaf(a.z, f3.z, acc[k][3]);
        acc[k][3] = fmaf(a.w, f3.w, acc[k][3]);
      }
    }

    // (3) exp + write buf[nxt] (probs loads have returned during GEMM)
    float (*bufn)[SC] = attn[nxt];
    #pragma unroll
    for (int r = 0; r < RPW; r++) {
      if (act[r]) {
        float m = smr[r], iv = sir[r];
        float4 a0, a1;
        a0.x = __expf(pr0[r].x - m) * iv;  a0.y = __expf(pr0[r].y - m) * iv;
        a0.z = __expf(pr0[r].z - m) * iv;  a0.w = __expf(pr0[r].w - m) * iv;
        a1.x = __expf(pr1[r].x - m) * iv;  a1.y = __expf(pr1[r].y - m) * iv;
        a1.z = __expf(pr1[r].z - m) * iv;  a1.w = __expf(pr1[r].w - m) * iv;
        *(float4*)&bufn[kk[r]][lane * 4]       = a0;
        *(float4*)&bufn[kk[r]][256 + lane * 4] = a1;
      }
    }

    // (4) single barrier: writes to buf[nxt] done before step s+1 reads it;
    //     reads of buf[cur] (pre-barrier) done before step s+1 overwrites it.
    __syncthreads();
  }

  // ---- reduce over lanes (hw) and store directly (no atomics) ----
  #pragma unroll
  for (int k = 0; k < KCLS; k++) {
    #pragma unroll
    for (int j = 0; j < 4; j++) {
      float v = acc[k][j];
      for (int off = 32; off > 0; off >>= 1) v += __shfl_xor(v, off);
      acc[k][j] = v;
    }
  }
  #pragma unroll
  for (int k = 0; k < KCLS; k++) {
    if (lane == k) {
      #pragma unroll
      for (int j = 0; j < 4; j++)
        out[(size_t)(b * CCH + c0 + j) * KCLS + k] = acc[k][j];
    }
  }
}

extern "C" void kernel_launch(void* const* d_in, const int* in_sizes, int n_in,
                              void* d_out, int out_size, void* d_ws, size_t ws_size,
                              hipStream_t stream) {
  const float* feat  = (const float*)d_in[0];   // [16, 512, 128, 128] f32
  const float* probs = (const float*)d_in[1];   // [16, 19, 128, 128] f32
  float* out   = (float*)d_out;                 // [16, 512, 19, 1] f32
  float* stats = (float*)d_ws;                  // 304 * 2 floats

  softmax_stats_kernel<<<BATCH * KCLS, 256, 0, stream>>>(probs, stats);
  // every output element written exactly once -> no memset, no atomics
  gather_kernel<<<BATCH * 32, 256, 0, stream>>>(feat, probs, stats, out);
}

// Round 5
// 197.646 us; speedup vs baseline: 2.2869x; 2.2869x over previous
//
#include <hip/hip_runtime.h>
#include <math.h>

#define BATCH 16
#define KCLS  19
#define CCH   512
#define HW    16384

#define SC    512          // hw staged per step
#define NSTEP (HW / SC)    // 32 steps, full HW per block
#define RPW   5            // ceil(KCLS/4) probs rows handled per wave

// ---------------- Kernel A: per-(b,k) softmax stats (max, 1/sum) ----------------
__global__ __launch_bounds__(256) void softmax_stats_kernel(
    const float* __restrict__ probs, float* __restrict__ stats) {
  const int bk = blockIdx.x;                      // 0..303
  const float4* row = (const float4*)(probs + (size_t)bk * HW);
  const int tid  = threadIdx.x;
  const int lane = tid & 63;
  const int wave = tid >> 6;
  __shared__ float red[4];

  float m = -1e30f;
  for (int i = tid; i < HW / 4; i += 256) {
    float4 v = row[i];
    m = fmaxf(m, fmaxf(fmaxf(v.x, v.y), fmaxf(v.z, v.w)));
  }
  for (int off = 32; off > 0; off >>= 1) m = fmaxf(m, __shfl_xor(m, off));
  if (lane == 0) red[wave] = m;
  __syncthreads();
  m = fmaxf(fmaxf(red[0], red[1]), fmaxf(red[2], red[3]));

  float s = 0.f;
  for (int i = tid; i < HW / 4; i += 256) {
    float4 v = row[i];
    s += __expf(v.x - m) + __expf(v.y - m) + __expf(v.z - m) + __expf(v.w - m);
  }
  for (int off = 32; off > 0; off >>= 1) s += __shfl_xor(s, off);
  __syncthreads();
  if (lane == 0) red[wave] = s;
  __syncthreads();
  if (tid == 0) {
    float total = red[0] + red[1] + red[2] + red[3];
    stats[2 * bk]     = m;
    stats[2 * bk + 1] = 1.0f / total;
  }
}

// ---------------- Kernel B: ctx[b,k,c] = sum_hw attn * feat ----------------
// 512 blocks x 256 thr: 2 blocks/CU resident (152 KB LDS), exactly one
// residency round. bid&15 = b -> each batch's blocks share one XCD (probs L2-hot).
// Pipeline per step s: [issue probs loads for s+1] [GEMM on buf[s&1]]
// [exp -> ds_write buf[s&1^1]] [one barrier].
// launch_bounds(256,1): VGPR cap 256. Any tighter bound (observed: cap=256/w)
// spills the ~220-reg live set (acc[19][4]=76 + prefetch 40 + feat + addr)
// -> 700 MB scratch traffic (rounds 1/2/4). DO NOT lower.
__global__ __launch_bounds__(256, 1) void gather_kernel(
    const float* __restrict__ feat, const float* __restrict__ probs,
    const float* __restrict__ stats, float* __restrict__ out) {
  __shared__ float attn[2][KCLS][SC];   // 76 KB

  const int bid   = blockIdx.x;
  const int b     = bid & 15;
  const int ctile = bid >> 4;          // 0..31
  const int tid   = threadIdx.x;
  const int wave  = tid >> 6;          // 4 waves
  const int lane  = tid & 63;
  const int c0    = ctile * 16 + wave * 4;

  // this wave's probs rows: k = wave + 4r (r<5); clamp dead row 19 -> 18
  int   kk[RPW];  bool act[RPW];  float smr[RPW], sir[RPW];
  #pragma unroll
  for (int r = 0; r < RPW; r++) {
    int k   = wave + 4 * r;
    act[r]  = (k < KCLS);
    kk[r]   = act[r] ? k : (KCLS - 1);
    smr[r]  = stats[2 * (b * KCLS + kk[r])];
    sir[r]  = stats[2 * (b * KCLS + kk[r]) + 1];
  }

  const float* fp = feat + ((size_t)(b * CCH + c0)) * HW;
  const float* pb = probs + (size_t)b * KCLS * HW;

  float acc[KCLS][4];
  #pragma unroll
  for (int k = 0; k < KCLS; k++)
    #pragma unroll
    for (int j = 0; j < 4; j++) acc[k][j] = 0.f;

  float4 pr0[RPW], pr1[RPW];

  // ---- prologue: stage step 0 into buf 0 ----
  #pragma unroll
  for (int r = 0; r < RPW; r++) {
    const float* pk = pb + (size_t)kk[r] * HW;
    pr0[r] = *(const float4*)(pk + lane * 4);
    pr1[r] = *(const float4*)(pk + 256 + lane * 4);
  }
  #pragma unroll
  for (int r = 0; r < RPW; r++) {
    if (act[r]) {
      float m = smr[r], iv = sir[r];
      float4 a0, a1;
      a0.x = __expf(pr0[r].x - m) * iv;  a0.y = __expf(pr0[r].y - m) * iv;
      a0.z = __expf(pr0[r].z - m) * iv;  a0.w = __expf(pr0[r].w - m) * iv;
      a1.x = __expf(pr1[r].x - m) * iv;  a1.y = __expf(pr1[r].y - m) * iv;
      a1.z = __expf(pr1[r].z - m) * iv;  a1.w = __expf(pr1[r].w - m) * iv;
      *(float4*)&attn[0][kk[r]][lane * 4]       = a0;
      *(float4*)&attn[0][kk[r]][256 + lane * 4] = a1;
    }
  }
  __syncthreads();

  // ---- main pipeline ----
  for (int s = 0; s < NSTEP; s++) {
    const int cur = s & 1, nxt = cur ^ 1;
    const int sn  = (s + 1 < NSTEP ? s + 1 : s) * SC;   // clamped prefetch target

    // (1) issue probs loads for step s+1 (latency hidden under GEMM)
    #pragma unroll
    for (int r = 0; r < RPW; r++) {
      const float* pk = pb + (size_t)kk[r] * HW + sn;
      pr0[r] = *(const float4*)(pk + lane * 4);
      pr1[r] = *(const float4*)(pk + 256 + lane * 4);
    }

    // (2) GEMM on buf[cur]
    const float* fs = fp + s * SC;
    const float (*bufc)[SC] = attn[cur];
    #pragma unroll
    for (int it = 0; it < SC; it += 256) {
      const int hw = it + lane * 4;
      float4 f0 = *(const float4*)(fs + (size_t)0 * HW + hw);
      float4 f1 = *(const float4*)(fs + (size_t)1 * HW + hw);
      float4 f2 = *(const float4*)(fs + (size_t)2 * HW + hw);
      float4 f3 = *(const float4*)(fs + (size_t)3 * HW + hw);
      #pragma unroll
      for (int k = 0; k < KCLS; k++) {
        float4 a = *(const float4*)&bufc[k][hw];
        acc[k][0] = fmaf(a.x, f0.x, acc[k][0]);
        acc[k][0] = fmaf(a.y, f0.y, acc[k][0]);
        acc[k][0] = fmaf(a.z, f0.z, acc[k][0]);
        acc[k][0] = fmaf(a.w, f0.w, acc[k][0]);
        acc[k][1] = fmaf(a.x, f1.x, acc[k][1]);
        acc[k][1] = fmaf(a.y, f1.y, acc[k][1]);
        acc[k][1] = fmaf(a.z, f1.z, acc[k][1]);
        acc[k][1] = fmaf(a.w, f1.w, acc[k][1]);
        acc[k][2] = fmaf(a.x, f2.x, acc[k][2]);
        acc[k][2] = fmaf(a.y, f2.y, acc[k][2]);
        acc[k][2] = fmaf(a.z, f2.z, acc[k][2]);
        acc[k][2] = fmaf(a.w, f2.w, acc[k][2]);
        acc[k][3] = fmaf(a.x, f3.x, acc[k][3]);
        acc[k][3] = fmaf(a.y, f3.y, acc[k][3]);
        acc[k][3] = fmaf(a.z, f3.z, acc[k][3]);
        acc[k][3] = fmaf(a.w, f3.w, acc[k][3]);
      }
    }

    // (3) exp + write buf[nxt] (probs loads have returned during GEMM)
    float (*bufn)[SC] = attn[nxt];
    #pragma unroll
    for (int r = 0; r < RPW; r++) {
      if (act[r]) {
        float m = smr[r], iv = sir[r];
        float4 a0, a1;
        a0.x = __expf(pr0[r].x - m) * iv;  a0.y = __expf(pr0[r].y - m) * iv;
        a0.z = __expf(pr0[r].z - m) * iv;  a0.w = __expf(pr0[r].w - m) * iv;
        a1.x = __expf(pr1[r].x - m) * iv;  a1.y = __expf(pr1[r].y - m) * iv;
        a1.z = __expf(pr1[r].z - m) * iv;  a1.w = __expf(pr1[r].w - m) * iv;
        *(float4*)&bufn[kk[r]][lane * 4]       = a0;
        *(float4*)&bufn[kk[r]][256 + lane * 4] = a1;
      }
    }

    // (4) single barrier: buf[nxt] writes visible before s+1 reads it;
    //     buf[cur] reads (pre-barrier) done before s+1 overwrites it.
    __syncthreads();
  }

  // ---- reduce over lanes (hw) and store directly (no atomics) ----
  #pragma unroll
  for (int k = 0; k < KCLS; k++) {
    #pragma unroll
    for (int j = 0; j < 4; j++) {
      float v = acc[k][j];
      for (int off = 32; off > 0; off >>= 1) v += __shfl_xor(v, off);
      acc[k][j] = v;
    }
  }
  #pragma unroll
  for (int k = 0; k < KCLS; k++) {
    if (lane == k) {
      #pragma unroll
      for (int j = 0; j < 4; j++)
        out[(size_t)(b * CCH + c0 + j) * KCLS + k] = acc[k][j];
    }
  }
}

extern "C" void kernel_launch(void* const* d_in, const int* in_sizes, int n_in,
                              void* d_out, int out_size, void* d_ws, size_t ws_size,
                              hipStream_t stream) {
  const float* feat  = (const float*)d_in[0];   // [16, 512, 128, 128] f32
  const float* probs = (const float*)d_in[1];   // [16, 19, 128, 128] f32
  float* out   = (float*)d_out;                 // [16, 512, 19, 1] f32
  float* stats = (float*)d_ws;                  // 304 * 2 floats

  softmax_stats_kernel<<<BATCH * KCLS, 256, 0, stream>>>(probs, stats);
  // every output element written exactly once -> no memset, no atomics
  gather_kernel<<<BATCH * 32, 256, 0, stream>>>(feat, probs, stats, out);
}

// Round 6
// 148.833 us; speedup vs baseline: 3.0369x; 1.3280x over previous
//
#include <hip/hip_runtime.h>
#include <math.h>

#define BATCH 16
#define KCLS  19
#define CCH   512
#define HW    16384

#define KSPLIT 16
#define KB     (HW / KSPLIT)   // 1024 k-range per block
#define BK     64              // k per chunk
#define NCHUNK (KB / BK)       // 16
#define NT     128             // channels per block

typedef __attribute__((ext_vector_type(8))) short  short8;
typedef __attribute__((ext_vector_type(4))) float  floatx4;

// fp32 -> bf16 round-to-nearest-even (finite inputs)
static __device__ __forceinline__ ushort f2bf(float x) {
  unsigned u = __float_as_uint(x);
  return (ushort)((u + 0x7FFFu + ((u >> 16) & 1u)) >> 16);
}

// ---------------- Kernel A: per-(b,k) softmax stats (max, 1/sum) ----------------
__global__ __launch_bounds__(256) void softmax_stats_kernel(
    const float* __restrict__ probs, float* __restrict__ stats) {
  const int bk = blockIdx.x;                      // 0..303
  const float4* row = (const float4*)(probs + (size_t)bk * HW);
  const int tid  = threadIdx.x;
  const int lane = tid & 63;
  const int wave = tid >> 6;
  __shared__ float red[4];

  float m = -1e30f;
  for (int i = tid; i < HW / 4; i += 256) {
    float4 v = row[i];
    m = fmaxf(m, fmaxf(fmaxf(v.x, v.y), fmaxf(v.z, v.w)));
  }
  for (int off = 32; off > 0; off >>= 1) m = fmaxf(m, __shfl_xor(m, off));
  if (lane == 0) red[wave] = m;
  __syncthreads();
  m = fmaxf(fmaxf(red[0], red[1]), fmaxf(red[2], red[3]));

  float s = 0.f;
  for (int i = tid; i < HW / 4; i += 256) {
    float4 v = row[i];
    s += __expf(v.x - m) + __expf(v.y - m) + __expf(v.z - m) + __expf(v.w - m);
  }
  for (int off = 32; off > 0; off >>= 1) s += __shfl_xor(s, off);
  __syncthreads();
  if (lane == 0) red[wave] = s;
  __syncthreads();
  if (tid == 0) {
    float total = red[0] + red[1] + red[2] + red[3];
    stats[2 * bk]     = m;
    stats[2 * bk + 1] = 1.0f / total;
  }
}

// ---------------- Kernel B: MFMA GEMM  C[19,512] += attn[19,K] * feat^T ----------------
// Grid 1024 = b(16) x ctile(4) x ksplit(16). bid&15=b -> batch pinned to one XCD
// (probs chunk L2-shared by its 4 ctile blocks). 4 blocks/CU (LDS 4x40960 =
// exactly 160 KiB), 16 waves/CU at <=128 VGPR (launch_bounds(256,2) cap; live ~100).
__global__ __launch_bounds__(256, 2) void gather_mfma(
    const float* __restrict__ feat, const float* __restrict__ probs,
    const float* __restrict__ stats, float* __restrict__ out) {
  // bf16 tiles, XOR-swizzled 16B granules: byte = row*128 + ((g ^ (row&7))*16)
  __shared__ __align__(16) short A[2][32][BK];   // 8 KB  (rows 19..31 garbage, outputs discarded)
  __shared__ __align__(16) short F[2][NT][BK];   // 32 KB

  const int bid = blockIdx.x;
  const int b   = bid & 15;
  const int r1  = bid >> 4;
  const int ct  = r1 & 3;            // 0..3  (128-channel tile)
  const int ks  = r1 >> 2;           // 0..15 (K split)
  const int k0  = ks * KB;

  const int tid  = threadIdx.x;
  const int wave = tid >> 6;         // 4 waves, each owns 32 channels
  const int lane = tid & 63;

  const float* fbase = feat  + ((size_t)(b * CCH + ct * NT)) * HW + k0;
  const float* pbase = probs + ((size_t)b * KCLS) * HW + k0;

  // probs staging: threads 0..151, one (row, 8-elem granule) each
  const int  prow = tid >> 3, pg = tid & 7;
  const bool pact = (tid < KCLS * 8);
  float pm = 0.f, pinv = 0.f;
  if (pact) {
    pm   = stats[2 * (b * KCLS + prow)];
    pinv = stats[2 * (b * KCLS + prow) + 1];
  }

  floatx4 acc00 = {0,0,0,0}, acc01 = {0,0,0,0}, acc10 = {0,0,0,0}, acc11 = {0,0,0,0};

  float4 fA0, fB0, fA1, fB1, fA2, fB2, fA3, fB3;   // 4 feat items x 8 floats
  float4 pA, pB;                                    // 1 probs item x 8 floats

  // feat item it: i = tid + 256*it -> ch = i>>3 (consecutive rows per 8 lanes), g = i&7
#define LOADC(c)                                                                \
  {                                                                             \
    const float* p0 = fbase + (size_t)((tid +   0) >> 3) * HW + (c) * BK + ((tid & 7) * 8); \
    const float* p1 = fbase + (size_t)((tid + 256) >> 3) * HW + (c) * BK + ((tid & 7) * 8); \
    const float* p2 = fbase + (size_t)((tid + 512) >> 3) * HW + (c) * BK + ((tid & 7) * 8); \
    const float* p3 = fbase + (size_t)((tid + 768) >> 3) * HW + (c) * BK + ((tid & 7) * 8); \
    fA0 = *(const float4*)p0;  fB0 = *(const float4*)(p0 + 4);                  \
    fA1 = *(const float4*)p1;  fB1 = *(const float4*)(p1 + 4);                  \
    fA2 = *(const float4*)p2;  fB2 = *(const float4*)(p2 + 4);                  \
    fA3 = *(const float4*)p3;  fB3 = *(const float4*)(p3 + 4);                  \
    if (pact) {                                                                 \
      const float* q = pbase + (size_t)prow * HW + (c) * BK + pg * 8;           \
      pA = *(const float4*)q;  pB = *(const float4*)(q + 4);                    \
    }                                                                           \
  }

#define WR1(buf, it, va, vb)                                                    \
  {                                                                             \
    int i  = tid + 256 * (it);                                                  \
    int ch = i >> 3, g = i & 7;                                                 \
    short8 v;                                                                   \
    v[0]=(short)f2bf(va.x); v[1]=(short)f2bf(va.y); v[2]=(short)f2bf(va.z); v[3]=(short)f2bf(va.w); \
    v[4]=(short)f2bf(vb.x); v[5]=(short)f2bf(vb.y); v[6]=(short)f2bf(vb.z); v[7]=(short)f2bf(vb.w); \
    *(short8*)((char*)&F[buf][0][0] + ch * 128 + ((g ^ (ch & 7)) * 16)) = v;    \
  }

#define WRITEC(buf)                                                             \
  {                                                                             \
    WR1(buf, 0, fA0, fB0)  WR1(buf, 1, fA1, fB1)                                \
    WR1(buf, 2, fA2, fB2)  WR1(buf, 3, fA3, fB3)                                \
    if (pact) {                                                                 \
      short8 v;                                                                 \
      v[0]=(short)f2bf(__expf(pA.x - pm) * pinv); v[1]=(short)f2bf(__expf(pA.y - pm) * pinv); \
      v[2]=(short)f2bf(__expf(pA.z - pm) * pinv); v[3]=(short)f2bf(__expf(pA.w - pm) * pinv); \
      v[4]=(short)f2bf(__expf(pB.x - pm) * pinv); v[5]=(short)f2bf(__expf(pB.y - pm) * pinv); \
      v[6]=(short)f2bf(__expf(pB.z - pm) * pinv); v[7]=(short)f2bf(__expf(pB.w - pm) * pinv); \
      *(short8*)((char*)&A[buf][0][0] + prow * 128 + ((pg ^ (prow & 7)) * 16)) = v; \
    }                                                                           \
  }

#define GEMMC(buf)                                                              \
  {                                                                             \
    _Pragma("unroll")                                                           \
    for (int kt = 0; kt < 2; kt++) {                                            \
      const int gA  = kt * 4 + (lane >> 4);                                     \
      const int rm0 = lane & 15;                                                \
      const int rm1 = 16 + rm0;                                                 \
      const int ch0 = wave * 32 + (lane & 15);                                  \
      const int ch1 = ch0 + 16;                                                 \
      short8 a0 = *(const short8*)((char*)&A[buf][0][0] + rm0 * 128 + ((gA ^ (rm0 & 7)) * 16)); \
      short8 a1 = *(const short8*)((char*)&A[buf][0][0] + rm1 * 128 + ((gA ^ (rm1 & 7)) * 16)); \
      short8 b0 = *(const short8*)((char*)&F[buf][0][0] + ch0 * 128 + ((gA ^ (ch0 & 7)) * 16)); \
      short8 b1 = *(const short8*)((char*)&F[buf][0][0] + ch1 * 128 + ((gA ^ (ch1 & 7)) * 16)); \
      acc00 = __builtin_amdgcn_mfma_f32_16x16x32_bf16(a0, b0, acc00, 0, 0, 0);  \
      acc01 = __builtin_amdgcn_mfma_f32_16x16x32_bf16(a0, b1, acc01, 0, 0, 0);  \
      acc10 = __builtin_amdgcn_mfma_f32_16x16x32_bf16(a1, b0, acc10, 0, 0, 0);  \
      acc11 = __builtin_amdgcn_mfma_f32_16x16x32_bf16(a1, b1, acc11, 0, 0, 0);  \
    }                                                                           \
  }

  // prologue
  LOADC(0);
  WRITEC(0);
  __syncthreads();

  for (int c = 0; c < NCHUNK; c++) {
    if (c + 1 < NCHUNK) LOADC(c + 1);      // issue next chunk's loads first
    GEMMC(c & 1);                           // consume current buffer
    if (c + 1 < NCHUNK) WRITEC((c + 1) & 1);// cvt+stage next (vmcnt hidden under GEMM)
    __syncthreads();                        // one barrier per chunk
  }

  // epilogue: C/D layout (16x16x32): col = lane&15 (channel), row = (lane>>4)*4 + j (class)
  {
    const int chb = ct * NT + wave * 32;
    const int rb  = (lane >> 4) * 4;
    const int cl  = lane & 15;
    #pragma unroll
    for (int j = 0; j < 4; j++) {
      int row = rb + j;
      // mt = 0 rows 0..15 always valid
      atomicAdd(&out[((size_t)(b * CCH + chb + cl))      * KCLS + row], acc00[j]);
      atomicAdd(&out[((size_t)(b * CCH + chb + 16 + cl)) * KCLS + row], acc01[j]);
      int row1 = 16 + row;
      if (row1 < KCLS) {
        atomicAdd(&out[((size_t)(b * CCH + chb + cl))      * KCLS + row1], acc10[j]);
        atomicAdd(&out[((size_t)(b * CCH + chb + 16 + cl)) * KCLS + row1], acc11[j]);
      }
    }
  }
#undef LOADC
#undef WR1
#undef WRITEC
#undef GEMMC
}

extern "C" void kernel_launch(void* const* d_in, const int* in_sizes, int n_in,
                              void* d_out, int out_size, void* d_ws, size_t ws_size,
                              hipStream_t stream) {
  const float* feat  = (const float*)d_in[0];   // [16, 512, 128, 128] f32
  const float* probs = (const float*)d_in[1];   // [16, 19, 128, 128] f32
  float* out   = (float*)d_out;                 // [16, 512, 19, 1] f32
  float* stats = (float*)d_ws;                  // 304 * 2 floats

  // K-split accumulates with atomics -> out must start at zero (harness poisons 0xAA)
  hipMemsetAsync(d_out, 0, (size_t)out_size * sizeof(float), stream);

  softmax_stats_kernel<<<BATCH * KCLS, 256, 0, stream>>>(probs, stats);
  gather_mfma<<<BATCH * 4 * KSPLIT, 256, 0, stream>>>(feat, probs, stats, out);
}

// Round 7
// 139.288 us; speedup vs baseline: 3.2450x; 1.0685x over previous
//
#include <hip/hip_runtime.h>
#include <math.h>

#define BATCH 16
#define KCLS  19
#define CCH   512
#define HW    16384

#define KSPLIT 16
#define KB     (HW / KSPLIT)   // 1024 k-range per block
#define BK     64              // k per chunk
#define NCHUNK (KB / BK)       // 16
#define NT     128             // channels per block
#define KPAD   20              // padded class dim in partials
#define BCN    (BATCH * CCH)   // 8192

typedef __attribute__((ext_vector_type(8))) short  short8;
typedef __attribute__((ext_vector_type(4))) float  floatx4;

typedef __attribute__((address_space(3))) void*        lds_ptr_t;
typedef const __attribute__((address_space(1))) void*  gbl_ptr_t;

// fp32 -> bf16 round-to-nearest-even (finite inputs)
static __device__ __forceinline__ ushort f2bf(float x) {
  unsigned u = __float_as_uint(x);
  return (ushort)((u + 0x7FFFu + ((u >> 16) & 1u)) >> 16);
}

static __device__ __forceinline__ short8 pack8(float4 a, float4 b) {
  short8 v;
  v[0] = (short)f2bf(a.x); v[1] = (short)f2bf(a.y);
  v[2] = (short)f2bf(a.z); v[3] = (short)f2bf(a.w);
  v[4] = (short)f2bf(b.x); v[5] = (short)f2bf(b.y);
  v[6] = (short)f2bf(b.z); v[7] = (short)f2bf(b.w);
  return v;
}

// ---------------- Kernel A: per-(b,k) softmax stats (max, 1/sum) ----------------
__global__ __launch_bounds__(256) void softmax_stats_kernel(
    const float* __restrict__ probs, float* __restrict__ stats) {
  const int bk = blockIdx.x;                      // 0..303
  const float4* row = (const float4*)(probs + (size_t)bk * HW);
  const int tid  = threadIdx.x;
  const int lane = tid & 63;
  const int wave = tid >> 6;
  __shared__ float red[4];

  float m = -1e30f;
  for (int i = tid; i < HW / 4; i += 256) {
    float4 v = row[i];
    m = fmaxf(m, fmaxf(fmaxf(v.x, v.y), fmaxf(v.z, v.w)));
  }
  for (int off = 32; off > 0; off >>= 1) m = fmaxf(m, __shfl_xor(m, off));
  if (lane == 0) red[wave] = m;
  __syncthreads();
  m = fmaxf(fmaxf(red[0], red[1]), fmaxf(red[2], red[3]));

  float s = 0.f;
  for (int i = tid; i < HW / 4; i += 256) {
    float4 v = row[i];
    s += __expf(v.x - m) + __expf(v.y - m) + __expf(v.z - m) + __expf(v.w - m);
  }
  for (int off = 32; off > 0; off >>= 1) s += __shfl_xor(s, off);
  __syncthreads();
  if (lane == 0) red[wave] = s;
  __syncthreads();
  if (tid == 0) {
    float total = red[0] + red[1] + red[2] + red[3];
    stats[2 * bk]     = m;
    stats[2 * bk + 1] = 1.0f / total;
  }
}

// ---------------- Kernel B: MFMA GEMM, feat via global_load_lds (fp32 LDS) ----------------
// Grid 1024 = b(16) x ctile(4) x ksplit(16); bid&15=b pins each batch to one XCD.
// LDS 72 KB -> 2 blocks/CU. Feat DMA'd fp32 into linear LDS with source-side XOR
// swizzle (g' = g ^ (ch&7), involution; same XOR on ds_read side) -> 2-way banks.
// cvt fp32->bf16 happens at frag read (each F element read exactly once/block).
__global__ __launch_bounds__(256, 1) void gather_mfma(
    const float* __restrict__ feat, const float* __restrict__ probs,
    const float* __restrict__ stats, float* __restrict__ part) {
  __shared__ __align__(16) float Fs[2][NT][BK];   // 64 KB fp32 feat tiles
  __shared__ __align__(16) short As[2][32][BK];   // 8 KB bf16 attn tiles (rows 19..31 garbage)

  const int bid = blockIdx.x;
  const int b   = bid & 15;
  const int r1  = bid >> 4;
  const int ct  = r1 & 3;            // 0..3  (128-channel tile)
  const int ks  = r1 >> 2;           // 0..15 (K split)
  const int k0  = ks * KB;

  const int tid  = threadIdx.x;
  const int wave = tid >> 6;         // 4 waves, each owns 32 channels
  const int lane = tid & 63;

  const float* fbase = feat  + ((size_t)(b * CCH + ct * NT)) * HW + k0;
  const float* pbase = probs + ((size_t)b * KCLS) * HW + k0;

  // probs staging: threads 0..151, one (row, 8-float granule) each
  const int  prow = tid >> 3, pg = tid & 7;
  const bool pact = (tid < KCLS * 8);
  float pm = 0.f, pinv = 0.f;
  if (pact) {
    pm   = stats[2 * (b * KCLS + prow)];
    pinv = stats[2 * (b * KCLS + prow) + 1];
  }

  floatx4 acc00 = {0,0,0,0}, acc01 = {0,0,0,0}, acc10 = {0,0,0,0}, acc11 = {0,0,0,0};
  float4 pA, pB;

  // DMA one F chunk: per wave 8 issues x 1KB (4 rows of 256B each).
  // lane l -> ch = base+ (l>>4), physical granule l&15; source granule (l&15)^(ch&7).
#define DMA_CHUNK(buf, c)                                                       \
  {                                                                             \
    char* lb = ((char*)Fs) + (buf) * 32768 + wave * 8192;                       \
    _Pragma("unroll")                                                           \
    for (int i = 0; i < 8; i++) {                                               \
      int ch = wave * 32 + i * 4 + (lane >> 4);                                 \
      const float* src = fbase + (size_t)ch * HW + (c) * BK                     \
                         + (((lane & 15) ^ (ch & 7)) << 2);                     \
      __builtin_amdgcn_global_load_lds((gbl_ptr_t)src,                          \
                                       (lds_ptr_t)(lb + i * 1024), 16, 0, 0);   \
    }                                                                           \
  }

#define PLOAD(c)                                                                \
  if (pact) {                                                                   \
    const float* q = pbase + (size_t)prow * HW + (c) * BK + pg * 8;             \
    pA = *(const float4*)q;  pB = *(const float4*)(q + 4);                      \
  }

#define PSTAGE(buf)                                                             \
  if (pact) {                                                                   \
    short8 v;                                                                   \
    v[0] = (short)f2bf(__expf(pA.x - pm) * pinv);                               \
    v[1] = (short)f2bf(__expf(pA.y - pm) * pinv);                               \
    v[2] = (short)f2bf(__expf(pA.z - pm) * pinv);                               \
    v[3] = (short)f2bf(__expf(pA.w - pm) * pinv);                               \
    v[4] = (short)f2bf(__expf(pB.x - pm) * pinv);                               \
    v[5] = (short)f2bf(__expf(pB.y - pm) * pinv);                               \
    v[6] = (short)f2bf(__expf(pB.z - pm) * pinv);                               \
    v[7] = (short)f2bf(__expf(pB.w - pm) * pinv);                               \
    *(short8*)((char*)As + (buf) * 4096 + prow * 128 + ((pg ^ (prow & 7)) << 4)) = v; \
  }

#define GEMMC(buf)                                                              \
  {                                                                             \
    const char* Ab = (const char*)As + (buf) * 4096;                            \
    const char* Fb = (const char*)Fs + (buf) * 32768;                           \
    _Pragma("unroll")                                                           \
    for (int kt = 0; kt < 2; kt++) {                                            \
      const int gA  = kt * 4 + (lane >> 4);                                     \
      const int rm0 = lane & 15;                                                \
      const int rm1 = 16 + rm0;                                                 \
      const int ch0 = wave * 32 + (lane & 15);                                  \
      const int ch1 = ch0 + 16;                                                 \
      short8 a0 = *(const short8*)(Ab + rm0 * 128 + ((gA ^ (rm0 & 7)) << 4));   \
      short8 a1 = *(const short8*)(Ab + rm1 * 128 + ((gA ^ (rm1 & 7)) << 4));   \
      float4 b0lo = *(const float4*)(Fb + ch0 * 256 + (((2 * gA)     ^ (ch0 & 7)) << 4)); \
      float4 b0hi = *(const float4*)(Fb + ch0 * 256 + (((2 * gA + 1) ^ (ch0 & 7)) << 4)); \
      float4 b1lo = *(const float4*)(Fb + ch1 * 256 + (((2 * gA)     ^ (ch1 & 7)) << 4)); \
      float4 b1hi = *(const float4*)(Fb + ch1 * 256 + (((2 * gA + 1) ^ (ch1 & 7)) << 4)); \
      short8 b0 = pack8(b0lo, b0hi);                                            \
      short8 b1 = pack8(b1lo, b1hi);                                            \
      acc00 = __builtin_amdgcn_mfma_f32_16x16x32_bf16(a0, b0, acc00, 0, 0, 0);  \
      acc01 = __builtin_amdgcn_mfma_f32_16x16x32_bf16(a0, b1, acc01, 0, 0, 0);  \
      acc10 = __builtin_amdgcn_mfma_f32_16x16x32_bf16(a1, b0, acc10, 0, 0, 0);  \
      acc11 = __builtin_amdgcn_mfma_f32_16x16x32_bf16(a1, b1, acc11, 0, 0, 0);  \
    }                                                                           \
  }

  // prologue: chunk 0
  DMA_CHUNK(0, 0);
  PLOAD(0);
  PSTAGE(0);
  __syncthreads();   // drains DMA vmcnt + A ds_writes

  for (int c = 0; c < NCHUNK; c++) {
    const int cur = c & 1, nxt = cur ^ 1;
    if (c + 1 < NCHUNK) { DMA_CHUNK(nxt, c + 1); PLOAD(c + 1); }
    GEMMC(cur);
    if (c + 1 < NCHUNK) PSTAGE(nxt);
    __syncthreads();   // next buffers complete; cur safe to overwrite next iter
  }

  // epilogue: plain float4 stores of partials. C/D layout: col=lane&15 (channel),
  // row=(lane>>4)*4+j (class). Rows >= 20 invalid -> only rb==0 stores rows 16..19
  // (row 19 is pad garbage, skipped by reduce).
  {
    const int chb = ct * NT + wave * 32;
    const int cl  = lane & 15;
    const int rb  = (lane >> 4) * 4;
    size_t bc0 = (size_t)b * CCH + chb + cl;
    size_t bc1 = bc0 + 16;
    float* p0 = part + ((size_t)ks * BCN + bc0) * KPAD + rb;
    float* p1 = part + ((size_t)ks * BCN + bc1) * KPAD + rb;
    *(float4*)p0 = *(float4*)&acc00;
    *(float4*)p1 = *(float4*)&acc01;
    if (rb == 0) {
      *(float4*)(p0 + 16) = *(float4*)&acc10;
      *(float4*)(p1 + 16) = *(float4*)&acc11;
    }
  }
#undef DMA_CHUNK
#undef PLOAD
#undef PSTAGE
#undef GEMMC
}

// ---------------- Kernel C: reduce partials over KSPLIT ----------------
__global__ __launch_bounds__(256) void reduce_kernel(
    const float* __restrict__ part, float* __restrict__ out) {
  const int gid = blockIdx.x * 256 + threadIdx.x;   // < BCN*KPAD = 163840
  const int bc = gid / KPAD, r = gid - bc * KPAD;
  if (r < KCLS) {
    float s = 0.f;
    #pragma unroll
    for (int k = 0; k < KSPLIT; k++)
      s += part[(size_t)k * (BCN * KPAD) + gid];
    out[(size_t)bc * KCLS + r] = s;
  }
}

extern "C" void kernel_launch(void* const* d_in, const int* in_sizes, int n_in,
                              void* d_out, int out_size, void* d_ws, size_t ws_size,
                              hipStream_t stream) {
  const float* feat  = (const float*)d_in[0];   // [16, 512, 128, 128] f32
  const float* probs = (const float*)d_in[1];   // [16, 19, 128, 128] f32
  float* out   = (float*)d_out;                 // [16, 512, 19, 1] f32
  float* stats = (float*)d_ws;                  // 608 floats
  float* part  = (float*)((char*)d_ws + 4096);  // [16][8192][20] = 10.5 MB partials

  softmax_stats_kernel<<<BATCH * KCLS, 256, 0, stream>>>(probs, stats);
  // partials fully written by plain stores (no zero-init needed), then reduced
  gather_mfma<<<BATCH * 4 * KSPLIT, 256, 0, stream>>>(feat, probs, stats, part);
  reduce_kernel<<<(BCN * KPAD) / 256, 256, 0, stream>>>(part, out);
}

// Round 8
// 137.094 us; speedup vs baseline: 3.2970x; 1.0160x over previous
//
#include <hip/hip_runtime.h>
#include <math.h>

#define BATCH 16
#define KCLS  19
#define CCH   512
#define HW    16384

#define KSPLIT 16
#define KB     (HW / KSPLIT)   // 1024 k-range per block
#define BK     64              // k per chunk
#define NCHUNK (KB / BK)       // 16
#define NT     128             // channels per block
#define KPAD   20
#define BCN    (BATCH * CCH)   // 8192

typedef __attribute__((ext_vector_type(8))) short  short8;
typedef __attribute__((ext_vector_type(4))) short  short4v;
typedef __attribute__((ext_vector_type(4))) float  floatx4;

// fp32 -> bf16 round-to-nearest-even (finite inputs)
static __device__ __forceinline__ ushort f2bf(float x) {
  unsigned u = __float_as_uint(x);
  return (ushort)((u + 0x7FFFu + ((u >> 16) & 1u)) >> 16);
}

static __device__ __forceinline__ short8 pack8(float4 a, float4 b) {
  short8 v;
  v[0] = (short)f2bf(a.x); v[1] = (short)f2bf(a.y);
  v[2] = (short)f2bf(a.z); v[3] = (short)f2bf(a.w);
  v[4] = (short)f2bf(b.x); v[5] = (short)f2bf(b.y);
  v[6] = (short)f2bf(b.z); v[7] = (short)f2bf(b.w);
  return v;
}

// ---------------- Kernel A: per-(b,k) softmax stats (max, 1/sum) ----------------
__global__ __launch_bounds__(256) void softmax_stats_kernel(
    const float* __restrict__ probs, float* __restrict__ stats) {
  const int bk = blockIdx.x;                      // 0..303
  const float4* row = (const float4*)(probs + (size_t)bk * HW);
  const int tid  = threadIdx.x;
  const int lane = tid & 63;
  const int wave = tid >> 6;
  __shared__ float red[4];

  float m = -1e30f;
  for (int i = tid; i < HW / 4; i += 256) {
    float4 v = row[i];
    m = fmaxf(m, fmaxf(fmaxf(v.x, v.y), fmaxf(v.z, v.w)));
  }
  for (int off = 32; off > 0; off >>= 1) m = fmaxf(m, __shfl_xor(m, off));
  if (lane == 0) red[wave] = m;
  __syncthreads();
  m = fmaxf(fmaxf(red[0], red[1]), fmaxf(red[2], red[3]));

  float s = 0.f;
  for (int i = tid; i < HW / 4; i += 256) {
    float4 v = row[i];
    s += __expf(v.x - m) + __expf(v.y - m) + __expf(v.z - m) + __expf(v.w - m);
  }
  for (int off = 32; off > 0; off >>= 1) s += __shfl_xor(s, off);
  __syncthreads();
  if (lane == 0) red[wave] = s;
  __syncthreads();
  if (tid == 0) {
    float total = red[0] + red[1] + red[2] + red[3];
    stats[2 * bk]     = m;
    stats[2 * bk + 1] = 1.0f / total;
  }
}

// ---------------- Kernel B: barrier-free MFMA GEMM ----------------
// C[19,512] per batch. A (attn, reused by all channel tiles) staged ONCE in LDS
// (38 KB bf16, XOR-swizzled granules). F (features, ZERO reuse) loaded straight
// from global into fragment registers -> no F-LDS, no barriers in the main loop.
// Grid 1024 = b(16) x ct(4) x ks(16); bid&15=b pins a batch's blocks to one XCD
// so the 4x probs re-read (A staging) hits that XCD's L2. 4 blocks/CU by LDS.
struct FSet { float4 v[8]; };   // one chunk's F fragments (constant-indexed only)

__global__ __launch_bounds__(256, 1) void gather_mfma(
    const float* __restrict__ feat, const float* __restrict__ probs,
    const float* __restrict__ stats, float* __restrict__ part) {
  __shared__ __align__(16) short A_all[KCLS][KB];   // 38 KB bf16 attn panel

  const int bid = blockIdx.x;
  const int b   = bid & 15;
  const int r1  = bid >> 4;
  const int ct  = r1 & 3;            // 0..3  (128-channel tile)
  const int ks  = r1 >> 2;           // 0..15 (K split)
  const int k0  = ks * KB;

  const int tid  = threadIdx.x;
  const int wave = tid >> 6;         // 4 waves, each owns 32 channels
  const int lane = tid & 63;

  const float* fbase = feat  + ((size_t)(b * CCH + ct * NT)) * HW + k0;
  const float* pbase = probs + ((size_t)b * KCLS) * HW + k0;

  // per-lane F fragment pointers: two channel rows, k-offset (lane>>4)*8
  const int ch0 = wave * 32 + (lane & 15);
  const int ch1 = ch0 + 16;
  const float* fptr0 = fbase + (size_t)ch0 * HW + (lane >> 4) * 8;
  const float* fptr1 = fbase + (size_t)ch1 * HW + (lane >> 4) * 8;

  floatx4 acc00 = {0,0,0,0}, acc01 = {0,0,0,0}, acc10 = {0,0,0,0}, acc11 = {0,0,0,0};

  FSet sA, sB;

  // fragments for chunk c: kt in {0,1}; v[kt*4+{0,1}] = ch0 lo/hi, v[kt*4+{2,3}] = ch1
#define LOADF(S, c)                                                             \
  {                                                                             \
    const int cb = (c) * BK;                                                    \
    S.v[0] = *(const float4*)(fptr0 + cb);                                      \
    S.v[1] = *(const float4*)(fptr0 + cb + 4);                                  \
    S.v[2] = *(const float4*)(fptr1 + cb);                                      \
    S.v[3] = *(const float4*)(fptr1 + cb + 4);                                  \
    S.v[4] = *(const float4*)(fptr0 + cb + 32);                                 \
    S.v[5] = *(const float4*)(fptr0 + cb + 36);                                 \
    S.v[6] = *(const float4*)(fptr1 + cb + 32);                                 \
    S.v[7] = *(const float4*)(fptr1 + cb + 36);                                 \
  }

  // A granule (16B = 8 bf16): logical g = c*8 + kt*4 + (lane>>4); phys = g ^ (row&7)
#define GEMMC(S, c)                                                             \
  {                                                                             \
    const char* Ab = (const char*)A_all;                                        \
    const int rm0  = lane & 15;                                                 \
    const int rm1  = 16 + (rm0 < 3 ? rm0 : 2);   /* clamp: rows 16..18 valid */ \
    _Pragma("unroll")                                                           \
    for (int kt = 0; kt < 2; kt++) {                                            \
      const int g = (c) * 8 + kt * 4 + (lane >> 4);                             \
      short8 a0 = *(const short8*)(Ab + rm0 * 2048 + ((g ^ (rm0 & 7)) << 4));   \
      short8 a1 = *(const short8*)(Ab + rm1 * 2048 + ((g ^ (rm1 & 7)) << 4));   \
      short8 b0 = pack8(S.v[kt * 4 + 0], S.v[kt * 4 + 1]);                      \
      short8 b1 = pack8(S.v[kt * 4 + 2], S.v[kt * 4 + 3]);                      \
      acc00 = __builtin_amdgcn_mfma_f32_16x16x32_bf16(a0, b0, acc00, 0, 0, 0);  \
      acc01 = __builtin_amdgcn_mfma_f32_16x16x32_bf16(a0, b1, acc01, 0, 0, 0);  \
      acc10 = __builtin_amdgcn_mfma_f32_16x16x32_bf16(a1, b0, acc10, 0, 0, 0);  \
      acc11 = __builtin_amdgcn_mfma_f32_16x16x32_bf16(a1, b1, acc11, 0, 0, 0);  \
    }                                                                           \
  }

  // issue chunk-0 F loads first (in flight during A staging)
  LOADF(sA, 0);

  // ---- stage the whole A panel: row j handled by all 256 threads (col4 = tid) ----
  for (int j = 0; j < KCLS; j++) {
    float m  = stats[2 * (b * KCLS + j)];
    float iv = stats[2 * (b * KCLS + j) + 1];
    float4 p = *(const float4*)(pbase + (size_t)j * HW + tid * 4);
    short4v v;
    v[0] = (short)f2bf(__expf(p.x - m) * iv);
    v[1] = (short)f2bf(__expf(p.y - m) * iv);
    v[2] = (short)f2bf(__expf(p.z - m) * iv);
    v[3] = (short)f2bf(__expf(p.w - m) * iv);
    // logical granule tid>>1, half tid&1; phys granule XOR row&7
    *(short4v*)((char*)A_all + j * 2048 + (((tid >> 1) ^ (j & 7)) << 4) + (tid & 1) * 8) = v;
  }
  __syncthreads();   // the only block-wide barrier

  // ---- barrier-free main loop, 2-deep register pipeline ----
  for (int c = 0; c < NCHUNK; c += 2) {
    LOADF(sB, c + 1);
    GEMMC(sA, c);
    if (c + 2 < NCHUNK) LOADF(sA, c + 2);
    GEMMC(sB, c + 1);
  }

  // ---- epilogue: partials, plain float4 stores ----
  // C/D layout: col = lane&15 (channel), row = (lane>>4)*4 + j (class)
  {
    const int chb = ct * NT + wave * 32;
    const int cl  = lane & 15;
    const int rb  = (lane >> 4) * 4;
    size_t bc0 = (size_t)b * CCH + chb + cl;
    size_t bc1 = bc0 + 16;
    float* p0 = part + ((size_t)ks * BCN + bc0) * KPAD + rb;
    float* p1 = part + ((size_t)ks * BCN + bc1) * KPAD + rb;
    *(float4*)p0 = *(float4*)&acc00;
    *(float4*)p1 = *(float4*)&acc01;
    if (rb == 0) {
      *(float4*)(p0 + 16) = *(float4*)&acc10;   // classes 16..18 (+pad 19)
      *(float4*)(p1 + 16) = *(float4*)&acc11;
    }
  }
#undef LOADF
#undef GEMMC
}

// ---------------- Kernel C: reduce partials over KSPLIT ----------------
__global__ __launch_bounds__(256) void reduce_kernel(
    const float* __restrict__ part, float* __restrict__ out) {
  const int gid = blockIdx.x * 256 + threadIdx.x;   // < BCN*KPAD = 163840
  const int bc = gid / KPAD, r = gid - bc * KPAD;
  if (r < KCLS) {
    float s = 0.f;
    #pragma unroll
    for (int k = 0; k < KSPLIT; k++)
      s += part[(size_t)k * (BCN * KPAD) + gid];
    out[(size_t)bc * KCLS + r] = s;
  }
}

extern "C" void kernel_launch(void* const* d_in, const int* in_sizes, int n_in,
                              void* d_out, int out_size, void* d_ws, size_t ws_size,
                              hipStream_t stream) {
  const float* feat  = (const float*)d_in[0];   // [16, 512, 128, 128] f32
  const float* probs = (const float*)d_in[1];   // [16, 19, 128, 128] f32
  float* out   = (float*)d_out;                 // [16, 512, 19, 1] f32
  float* stats = (float*)d_ws;                  // 608 floats
  float* part  = (float*)((char*)d_ws + 4096);  // [16][8192][20] = 10.5 MB

  softmax_stats_kernel<<<BATCH * KCLS, 256, 0, stream>>>(probs, stats);
  gather_mfma<<<BATCH * 4 * KSPLIT, 256, 0, stream>>>(feat, probs, stats, part);
  reduce_kernel<<<(BCN * KPAD) / 256, 256, 0, stream>>>(part, out);
}